// Round 7
// baseline (984.743 us; speedup 1.0000x reference)
//
#include <hip/hip_runtime.h>

#define N_TOK 32768
#define N_EMB 4096
#define DIM 256

typedef short bf16x8 __attribute__((ext_vector_type(8)));
typedef float f32x4 __attribute__((ext_vector_type(4)));
typedef unsigned short us8 __attribute__((ext_vector_type(8)));

// ---------------- ws layout ----------------
// [0, 16384)        counts    uint[4096]
// [16384, 16388)    loss_acc  float
// [16896, 33280)    e2_np     float[4096]
// [33280, 164352)   x2_np     float[32768]
// Big scratch (bf16, MFMA-fragment-shuffled) lives 256B-aligned inside the
// encodings output region (536 MB), overwritten by k_onehot afterwards.

static __device__ __forceinline__ unsigned short f2bf(float f) {
    unsigned int u = __float_as_uint(f);
    u = (u + 0x7fffu + ((u >> 16) & 1u)) >> 16;   // RTN-even
    return (unsigned short)u;
}

// ---------------- numpy-pairwise fp32 row norms (r3-proven bit-exact) ------
__device__ __forceinline__ float pw128_sq(const float4* a4) {
#pragma clang fp contract(off)
    float4 v0 = a4[0], v1 = a4[1];
    float r0 = v0.x * v0.x, r1 = v0.y * v0.y, r2 = v0.z * v0.z, r3 = v0.w * v0.w;
    float r4 = v1.x * v1.x, r5 = v1.y * v1.y, r6 = v1.z * v1.z, r7 = v1.w * v1.w;
    #pragma unroll
    for (int i = 1; i < 16; ++i) {
        v0 = a4[2 * i]; v1 = a4[2 * i + 1];
        float s;
        s = v0.x * v0.x; r0 += s;
        s = v0.y * v0.y; r1 += s;
        s = v0.z * v0.z; r2 += s;
        s = v0.w * v0.w; r3 += s;
        s = v1.x * v1.x; r4 += s;
        s = v1.y * v1.y; r5 += s;
        s = v1.z * v1.z; r6 += s;
        s = v1.w * v1.w; r7 += s;
    }
    return ((r0 + r1) + (r2 + r3)) + ((r4 + r5) + (r6 + r7));
}

__global__ __launch_bounds__(256) void k_norm_np(const float* __restrict__ src,
                                                 float* __restrict__ dst, int nrows) {
#pragma clang fp contract(off)
    int row = blockIdx.x * 256 + threadIdx.x;
    if (row >= nrows) return;
    const float4* a = (const float4*)(src + (size_t)row * DIM);
    float lo = pw128_sq(a);
    float hi = pw128_sq(a + 32);
    dst[row] = lo + hi;
}

// ---------------- bf16 cast + MFMA-fragment shuffle ----------------
// Granule = 1KB (tile T of 16 rows, k-chunk C of 32):
// lane l's 16B = row T*16+(l&15), k = C*32 + (l>>4)*8 .. +8.
__global__ __launch_bounds__(256) void k_shuf1(const float* __restrict__ src,
                                               unsigned short* __restrict__ hi) {
    int tid = blockIdx.x * 256 + threadIdx.x;
    int b = tid >> 6, lane = tid & 63;
    int T = b >> 3, C = b & 7;
    int row = T * 16 + (lane & 15);
    int col = C * 32 + (lane >> 4) * 8;
    const float* s = src + (size_t)row * DIM + col;
    us8 h;
    #pragma unroll
    for (int j = 0; j < 8; ++j) h[j] = f2bf(s[j]);
    *(us8*)(hi + (size_t)tid * 8) = h;
}

// ---------------- MFMA scoring + top-3 + np-exact refinement ----------------
// r4/r6-proven skeleton. Block: 32 tokens x all codes (jt steps of 256).
// 4 waves, wave = M32 x N64. A = bf16(x) staged once in LDS (16 KB);
// B = bf16(w) register-direct from L2-resident Wh (2 MB < 4 MiB/XCD).
// Dot noise sigma ~6.7e-6; margin 1.5e-4 covers np bucket ulp(<=512)=6.1e-5
// + 10 sigma, feeding the r3-proven np-fp32 bucket-exact refinement.
// LDS 48 KB -> 3 blocks/CU.
__global__ __launch_bounds__(256, 3) void k_score_mfma(
        const float* __restrict__ x, const float* __restrict__ w,
        const float* __restrict__ e2_np, const float* __restrict__ x2_np,
        const unsigned short* __restrict__ Xh,
        const unsigned short* __restrict__ Wh,
        float* __restrict__ out_idx, unsigned int* __restrict__ counts) {
    __shared__ __align__(16) short Abuf[8192];    // [tile(2)][C(8)][lane][8] = 16 KB
    __shared__ __align__(16) float Sc[32 * 256];  // XOR-swizzled scores, 32 KB

    const int t = threadIdx.x;
    const int wave = t >> 6, lane = t & 63;
    const int tok0 = blockIdx.x * 32;
    const int tkn = t & 31, seg = t >> 5;   // reduction mapping: 8 threads/token

    // ---- stage A (2 tiles x 8 chunks x 1KB) ----
    #pragma unroll
    for (int i = 0; i < 4; ++i) {
        int idx = wave * 4 + i;             // 0..15
        int tile = idx >> 3, C = idx & 7;
        int Tg = blockIdx.x * 2 + tile;
        const unsigned short* src = Xh + ((size_t)(Tg * 8 + C) * 64 + lane) * 8;
        __builtin_amdgcn_global_load_lds(
            (const __attribute__((address_space(1))) unsigned int*)src,
            (__attribute__((address_space(3))) unsigned int*)(Abuf + idx * 512),
            16, 0, 0);
    }
    __syncthreads();

    float d0 = -3.4e38f, d1 = -3.4e38f, d2 = -3.4e38f;
    int   i0 = 0, i1 = 0, i2 = 0;
    const int q = lane >> 4, c = lane & 15;

    for (int jt = 0; jt < N_EMB; jt += 256) {
        const int U0 = (jt >> 4) + wave * 4;   // my 4 code-tiles
        f32x4 acc[2][4] = {};
        #pragma unroll
        for (int C = 0; C < 8; ++C) {
            bf16x8 ah[2], bh[4];
            #pragma unroll
            for (int m = 0; m < 2; ++m)
                ah[m] = *(const bf16x8*)(Abuf + (size_t)(m * 8 + C) * 512 + lane * 8);
            #pragma unroll
            for (int n = 0; n < 4; ++n) {
                size_t boff = (((size_t)(U0 + n) * 8 + C) * 64 + lane) * 8;
                bh[n] = *(const bf16x8*)(Wh + boff);
            }
            #pragma unroll
            for (int m = 0; m < 2; ++m)
                #pragma unroll
                for (int n = 0; n < 4; ++n)
                    acc[m][n] = __builtin_amdgcn_mfma_f32_16x16x32_bf16(ah[m], bh[n], acc[m][n], 0, 0, 0);
        }
        __syncthreads();   // previous top-3 readers done
        // C/D layout: token row = m*16 + q*4 + r, code col = n*16 + c.
        // Swizzle: store col' = col ^ row (row<32) -> 2-way read aliasing (free).
        #pragma unroll
        for (int m = 0; m < 2; ++m) {
            int row = m * 16 + q * 4;
            #pragma unroll
            for (int n = 0; n < 4; ++n) {
                int col = wave * 64 + n * 16 + c;
                #pragma unroll
                for (int r = 0; r < 4; ++r)
                    Sc[(row + r) * 256 + (col ^ (row + r))] = acc[m][n][r];
            }
        }
        __syncthreads();
        // top-3 max-dot per (token, 32-code segment)
        int rb = tkn * 256 + seg * 32;
        int cbase = jt + seg * 32;
        #pragma unroll 8
        for (int i = 0; i < 32; ++i) {
            float d = Sc[rb + (i ^ tkn)];
            if (d > d2) {
                int code = cbase + i;
                if (d > d0)      { d2 = d1; i2 = i1; d1 = d0; i1 = i0; d0 = d; i0 = code; }
                else if (d > d1) { d2 = d1; i2 = i1; d1 = d;  i1 = code; }
                else             { d2 = d;  i2 = code; }
            }
        }
    }

    // ---- per-token best approx dot ----
    float* Red_d = Sc;                 // reuse (Sc dead now)
    int*   Red_i = (int*)(Sc + 256);
    __syncthreads();
    Red_d[tkn * 8 + seg] = d0;
    __syncthreads();
    float bv = -3.4e38f;
    #pragma unroll
    for (int k = 0; k < 8; ++k) bv = fmaxf(bv, Red_d[tkn * 8 + k]);

    // ---- np-fp32-exact refinement (r3-proven) ----
    float bd = 3.4e38f;
    int bi = 0x7fffffff;
    float x2 = x2_np[tok0 + tkn];
    const float4* xr = (const float4*)(x + (size_t)(tok0 + tkn) * DIM);
    float dv[3] = {d0, d1, d2};
    int   iv[3] = {i0, i1, i2};
    for (int cn = 0; cn < 3; ++cn) {
        if (dv[cn] >= bv - 1.5e-4f) {
            int code = iv[cn];
            const float4* wr = (const float4*)(w + (size_t)code * DIM);
            double dot = 0.0;
            for (int g = 0; g < 64; ++g) {
                float4 xv = xr[g];
                float4 wv = wr[g];
                dot += (double)xv.x * (double)wv.x;
                dot += (double)xv.y * (double)wv.y;
                dot += (double)xv.z * (double)wv.z;
                dot += (double)xv.w * (double)wv.w;
            }
            {
#pragma clang fp contract(off)
                float M  = (float)dot;          // BLAS sgemm entry (~2e-9)
                float S  = x2 + e2_np[code];    // np broadcast add (fp32)
                float dd = S - 2.0f * M;        // fp32 sub -> ulp(~300) bucket
                if (dd < bd || (dd == bd && code < bi)) { bd = dd; bi = code; }
            }
        }
    }
    __syncthreads();
    Red_d[tkn * 8 + seg] = bd;
    Red_i[tkn * 8 + seg] = bi;
    __syncthreads();
    if (t < 32) {
        float fv = Red_d[t * 8];
        int   fi = Red_i[t * 8];
        #pragma unroll
        for (int k = 1; k < 8; ++k) {
            float v = Red_d[t * 8 + k];
            int  ii = Red_i[t * 8 + k];
            if (v < fv || (v == fv && ii < fi)) { fv = v; fi = ii; }
        }
        out_idx[tok0 + t] = (float)fi;
        atomicAdd(&counts[fi], 1u);
    }
}

// ---------------- gather quantized + loss ----------------
__global__ __launch_bounds__(256) void k_gather(const float* __restrict__ x,
                                                const float* __restrict__ w,
                                                const float* __restrict__ out_idx,
                                                float* __restrict__ outq,
                                                float* __restrict__ loss_acc) {
    int gid = blockIdx.x * 256 + threadIdx.x;
    int token = gid >> 6;
    int d4 = gid & 63;
    int idx = (int)out_idx[token];
    float4 q  = ((const float4*)(w + (size_t)idx * DIM))[d4];
    float4 xv = ((const float4*)x)[gid];
    ((float4*)outq)[gid] = q;
    float dx = q.x - xv.x, dy = q.y - xv.y, dz = q.z - xv.z, dw = q.w - xv.w;
    float sse = dx * dx + dy * dy + dz * dz + dw * dw;
    #pragma unroll
    for (int off = 32; off > 0; off >>= 1) sse += __shfl_down(sse, off, 64);
    __shared__ float sred[4];
    int lane = threadIdx.x & 63, wv = threadIdx.x >> 6;
    if (lane == 0) sred[wv] = sse;
    __syncthreads();
    if (threadIdx.x == 0)
        atomicAdd(loss_acc, sred[0] + sred[1] + sred[2] + sred[3]);
}

// ---------------- one-hot encodings ----------------
__global__ __launch_bounds__(256) void k_onehot(const float* __restrict__ out_idx,
                                                float* __restrict__ enc) {
    int token = blockIdx.x;
    int idx = (int)out_idx[token];
    float4* row = (float4*)(enc + (size_t)token * N_EMB);
    #pragma unroll
    for (int p = 0; p < 4; ++p) {
        int g = threadIdx.x + 256 * p;
        float4 v = make_float4(0.f, 0.f, 0.f, 0.f);
        int d0 = g * 4;
        if (idx >= d0 && idx < d0 + 4) ((float*)&v)[idx - d0] = 1.0f;
        row[g] = v;
    }
}

// ---------------- perplexity + loss finalize ----------------
__global__ __launch_bounds__(256) void k_final(const unsigned int* __restrict__ counts,
                                               const float* __restrict__ loss_acc,
                                               float* __restrict__ out_perp,
                                               float* __restrict__ out_loss) {
    __shared__ float sred[4];
    int t = threadIdx.x;
    float h = 0.f;
    for (int k = t; k < N_EMB; k += 256) {
        float p = (float)counts[k] * (1.0f / N_TOK);
        h += p * logf(p + 1e-10f);
    }
    #pragma unroll
    for (int off = 32; off > 0; off >>= 1) h += __shfl_down(h, off, 64);
    if ((t & 63) == 0) sred[t >> 6] = h;
    __syncthreads();
    if (t == 0) {
        float s = sred[0] + sred[1] + sred[2] + sred[3];
        *out_perp = expf(-s);
        *out_loss = loss_acc[0] * 1.25f / 8388608.0f;
    }
}

extern "C" void kernel_launch(void* const* d_in, const int* in_sizes, int n_in,
                              void* d_out, int out_size, void* d_ws, size_t ws_size,
                              hipStream_t stream) {
    const float* x = (const float*)d_in[0];
    const float* w = (const float*)d_in[1];
    float* out  = (float*)d_out;
    float* out0 = out;                       // quantized_st [32768*256]
    float* out1 = out0 + 8388608;            // perplexity   [1]
    float* out2 = out1 + 1;                  // encodings    [32768*4096]
    float* out3 = out2 + 134217728;          // indices      [32768] (as float)
    float* out4 = out3 + 32768;              // loss         [1]

    unsigned int* counts = (unsigned int*)d_ws;
    float* loss_acc = (float*)((char*)d_ws + 16384);
    float* e2_np    = (float*)((char*)d_ws + 16896);
    float* x2_np    = (float*)((char*)d_ws + 33280);

    // bf16 shuffled scratch inside the encodings region (18 MB of 536 MB),
    // 256B-aligned; k_onehot overwrites it after k_score_mfma consumed it.
    uintptr_t sb = ((uintptr_t)out2 + 255) & ~(uintptr_t)255;
    unsigned short* Xh = (unsigned short*)sb;     // 16 MB
    unsigned short* Wh = Xh + 8388608;            // 2 MB

    hipMemsetAsync(d_ws, 0, 16640, stream);
    k_norm_np<<<N_EMB / 256, 256, 0, stream>>>(w, e2_np, N_EMB);
    k_norm_np<<<N_TOK / 256, 256, 0, stream>>>(x, x2_np, N_TOK);
    k_shuf1<<<N_TOK * DIM / 8 / 256, 256, 0, stream>>>(x, Xh);
    k_shuf1<<<N_EMB * DIM / 8 / 256, 256, 0, stream>>>(w, Wh);
    k_score_mfma<<<N_TOK / 32, 256, 0, stream>>>(x, w, e2_np, x2_np,
                                                 Xh, Wh, out3, counts);
    k_gather<<<N_TOK * 64 / 256, 256, 0, stream>>>(x, w, out3, out0, loss_acc);
    k_onehot<<<N_TOK, 256, 0, stream>>>(out3, out2);
    k_final<<<1, 256, 0, stream>>>(counts, loss_acc, out1, out4);
}

// Round 8
// 966.800 us; speedup vs baseline: 1.0186x; 1.0186x over previous
//
#include <hip/hip_runtime.h>

#define N_TOK 32768
#define N_EMB 4096
#define DIM 256

typedef short bf16x8 __attribute__((ext_vector_type(8)));
typedef float f32x4 __attribute__((ext_vector_type(4)));
typedef unsigned short us8 __attribute__((ext_vector_type(8)));

// ---------------- ws layout ----------------
// [0, 16384)        counts    uint[4096]
// [16384, 16388)    loss_acc  float
// [16896, 33280)    e2_np     float[4096]
// [33280, 164352)   x2_np     float[32768]
// bf16 MFMA-shuffled scratch lives 256B-aligned in the encodings output
// region (536 MB), overwritten by k_onehot afterwards.

static __device__ __forceinline__ unsigned short f2bf(float f) {
    unsigned int u = __float_as_uint(f);
    u = (u + 0x7fffu + ((u >> 16) & 1u)) >> 16;   // RTN-even
    return (unsigned short)u;
}

// ---------------- numpy-pairwise fp32 row norms (r3-proven bit-exact) ------
__device__ __forceinline__ float pw128_sq(const float4* a4) {
#pragma clang fp contract(off)
    float4 v0 = a4[0], v1 = a4[1];
    float r0 = v0.x * v0.x, r1 = v0.y * v0.y, r2 = v0.z * v0.z, r3 = v0.w * v0.w;
    float r4 = v1.x * v1.x, r5 = v1.y * v1.y, r6 = v1.z * v1.z, r7 = v1.w * v1.w;
    #pragma unroll
    for (int i = 1; i < 16; ++i) {
        v0 = a4[2 * i]; v1 = a4[2 * i + 1];
        float s;
        s = v0.x * v0.x; r0 += s;
        s = v0.y * v0.y; r1 += s;
        s = v0.z * v0.z; r2 += s;
        s = v0.w * v0.w; r3 += s;
        s = v1.x * v1.x; r4 += s;
        s = v1.y * v1.y; r5 += s;
        s = v1.z * v1.z; r6 += s;
        s = v1.w * v1.w; r7 += s;
    }
    return ((r0 + r1) + (r2 + r3)) + ((r4 + r5) + (r6 + r7));
}

__global__ __launch_bounds__(256) void k_norm_np(const float* __restrict__ src,
                                                 float* __restrict__ dst, int nrows) {
#pragma clang fp contract(off)
    int row = blockIdx.x * 256 + threadIdx.x;
    if (row >= nrows) return;
    const float4* a = (const float4*)(src + (size_t)row * DIM);
    float lo = pw128_sq(a);
    float hi = pw128_sq(a + 32);
    dst[row] = lo + hi;
}

// ---------------- bf16 cast + MFMA-fragment shuffle ----------------
// Granule = 1KB (tile T of 16 rows, k-chunk C of 32):
// lane l's 16B = row T*16+(l&15), k = C*32 + (l>>4)*8 .. +8.
__global__ __launch_bounds__(256) void k_shuf1(const float* __restrict__ src,
                                               unsigned short* __restrict__ hi) {
    int tid = blockIdx.x * 256 + threadIdx.x;
    int b = tid >> 6, lane = tid & 63;
    int T = b >> 3, C = b & 7;
    int row = T * 16 + (lane & 15);
    int col = C * 32 + (lane >> 4) * 8;
    const float* s = src + (size_t)row * DIM + col;
    us8 h;
    #pragma unroll
    for (int j = 0; j < 8; ++j) h[j] = f2bf(s[j]);
    *(us8*)(hi + (size_t)tid * 8) = h;
}

// ---------------- MFMA scoring: threshold two-pass + np-exact refinement ---
// Block: 32 tokens x all codes. 4 waves split codes, share tokens.
// Pass 1: barrier-free jt loop, in-register per-token running max of dots.
// Pass 2: identical (bit-deterministic) MFMAs; codes with acc >= max-1.5e-4
// pushed to per-token LDS list (expected ~1.2/token). Refinement = r3-proven
// np-fp32 bucket replay (fp64 dot -> fp32 ops), min-bucket + lowest-index.
// Margin: bf16 noise 10sigma=6.7e-5 + e2 range/2 = 7.6e-6 + bucket 1.5e-5
// << 1.5e-4 (r6/r7-proven). Barriers: 4 total (was 32).
__global__ __launch_bounds__(256, 4) void k_score_mfma(
        const float* __restrict__ x, const float* __restrict__ w,
        const float* __restrict__ e2_np, const float* __restrict__ x2_np,
        const unsigned short* __restrict__ Xh,
        const unsigned short* __restrict__ Wh,
        float* __restrict__ out_idx, unsigned int* __restrict__ counts) {
    __shared__ __align__(16) short Abuf[8192];   // [tile(2)][C(8)][lane][8] = 16 KB
    __shared__ float Tmax[4][32];
    __shared__ unsigned int ccnt[32];
    __shared__ int clist[32][16];
    __shared__ float Red_d[32 * 8];
    __shared__ int   Red_i[32 * 8];

    const int t = threadIdx.x;
    const int wave = t >> 6, lane = t & 63;
    const int tok0 = blockIdx.x * 32;
    const int q = lane >> 4, c = lane & 15;

    // ---- stage A (2 tiles x 8 chunks x 1KB), r7-proven ----
    #pragma unroll
    for (int i = 0; i < 4; ++i) {
        int idx = wave * 4 + i;             // 0..15
        int tile = idx >> 3, C = idx & 7;
        int Tg = blockIdx.x * 2 + tile;
        const unsigned short* src = Xh + ((size_t)(Tg * 8 + C) * 64 + lane) * 8;
        __builtin_amdgcn_global_load_lds(
            (const __attribute__((address_space(1))) unsigned int*)src,
            (__attribute__((address_space(3))) unsigned int*)(Abuf + idx * 512),
            16, 0, 0);
    }
    if (t < 32) ccnt[t] = 0;
    __syncthreads();

    // ---- pass 1: per-token max dot (no LDS, no barriers) ----
    float vmax[8];
    #pragma unroll
    for (int s = 0; s < 8; ++s) vmax[s] = -3.4e38f;
    for (int jt = 0; jt < N_EMB; jt += 256) {
        const int U0 = (jt >> 4) + wave * 4;
        f32x4 acc[2][4] = {};
        #pragma unroll
        for (int C = 0; C < 8; ++C) {
            bf16x8 ah[2], bh[4];
            #pragma unroll
            for (int m = 0; m < 2; ++m)
                ah[m] = *(const bf16x8*)(Abuf + (size_t)(m * 8 + C) * 512 + lane * 8);
            #pragma unroll
            for (int n = 0; n < 4; ++n)
                bh[n] = *(const bf16x8*)(Wh + (((size_t)(U0 + n) * 8 + C) * 64 + lane) * 8);
            #pragma unroll
            for (int m = 0; m < 2; ++m)
                #pragma unroll
                for (int n = 0; n < 4; ++n)
                    acc[m][n] = __builtin_amdgcn_mfma_f32_16x16x32_bf16(ah[m], bh[n], acc[m][n], 0, 0, 0);
        }
        #pragma unroll
        for (int m = 0; m < 2; ++m)
            #pragma unroll
            for (int n = 0; n < 4; ++n)
                #pragma unroll
                for (int r = 0; r < 4; ++r)
                    vmax[m * 4 + r] = fmaxf(vmax[m * 4 + r], acc[m][n][r]);
    }
    // reduce over the 16 c-lanes of each q-group
    #pragma unroll
    for (int off = 1; off < 16; off <<= 1)
        #pragma unroll
        for (int s = 0; s < 8; ++s)
            vmax[s] = fmaxf(vmax[s], __shfl_xor(vmax[s], off));
    if (c == 0) {
        #pragma unroll
        for (int m = 0; m < 2; ++m)
            #pragma unroll
            for (int r = 0; r < 4; ++r)
                Tmax[wave][m * 16 + q * 4 + r] = vmax[m * 4 + r];
    }
    __syncthreads();
    if (t < 32) {
        float mx = fmaxf(fmaxf(Tmax[0][t], Tmax[1][t]),
                         fmaxf(Tmax[2][t], Tmax[3][t]));
        Tmax[0][t] = mx - 1.5e-4f;     // threshold
    }
    __syncthreads();
    float thr[8];
    #pragma unroll
    for (int m = 0; m < 2; ++m)
        #pragma unroll
        for (int r = 0; r < 4; ++r)
            thr[m * 4 + r] = Tmax[0][m * 16 + q * 4 + r];

    // ---- pass 2: recompute (bit-identical), collect candidates ----
    for (int jt = 0; jt < N_EMB; jt += 256) {
        const int U0 = (jt >> 4) + wave * 4;
        f32x4 acc[2][4] = {};
        #pragma unroll
        for (int C = 0; C < 8; ++C) {
            bf16x8 ah[2], bh[4];
            #pragma unroll
            for (int m = 0; m < 2; ++m)
                ah[m] = *(const bf16x8*)(Abuf + (size_t)(m * 8 + C) * 512 + lane * 8);
            #pragma unroll
            for (int n = 0; n < 4; ++n)
                bh[n] = *(const bf16x8*)(Wh + (((size_t)(U0 + n) * 8 + C) * 64 + lane) * 8);
            #pragma unroll
            for (int m = 0; m < 2; ++m)
                #pragma unroll
                for (int n = 0; n < 4; ++n)
                    acc[m][n] = __builtin_amdgcn_mfma_f32_16x16x32_bf16(ah[m], bh[n], acc[m][n], 0, 0, 0);
        }
        #pragma unroll
        for (int m = 0; m < 2; ++m)
            #pragma unroll
            for (int n = 0; n < 4; ++n)
                #pragma unroll
                for (int r = 0; r < 4; ++r)
                    if (acc[m][n][r] >= thr[m * 4 + r]) {
                        int tokl = m * 16 + q * 4 + r;
                        int code = (U0 + n) * 16 + c;
                        unsigned int p = atomicAdd(&ccnt[tokl], 1u);
                        if (p < 16) clist[tokl][p] = code;
                    }
    }
    __syncthreads();

    // ---- np-fp32-exact refinement: 8 threads/token over the list ----
    {
        int token = t >> 3, slot = t & 7;
        int cnt = (int)ccnt[token]; if (cnt > 16) cnt = 16;
        float bd = 3.4e38f;
        int bi = 0x7fffffff;
        float x2 = x2_np[tok0 + token];
        const float4* xr = (const float4*)(x + (size_t)(tok0 + token) * DIM);
        for (int k = slot; k < cnt; k += 8) {
            int code = clist[token][k];
            const float4* wr = (const float4*)(w + (size_t)code * DIM);
            double dot = 0.0;
            for (int g = 0; g < 64; ++g) {
                float4 xv = xr[g];
                float4 wv = wr[g];
                dot += (double)xv.x * (double)wv.x;
                dot += (double)xv.y * (double)wv.y;
                dot += (double)xv.z * (double)wv.z;
                dot += (double)xv.w * (double)wv.w;
            }
            {
#pragma clang fp contract(off)
                float M  = (float)dot;          // BLAS sgemm entry (~2e-9)
                float S  = x2 + e2_np[code];    // np broadcast add (fp32)
                float dd = S - 2.0f * M;        // fp32 sub -> ulp bucket
                if (dd < bd || (dd == bd && code < bi)) { bd = dd; bi = code; }
            }
        }
        Red_d[token * 8 + slot] = bd;
        Red_i[token * 8 + slot] = bi;
    }
    __syncthreads();
    if (t < 32) {
        float fv = Red_d[t * 8];
        int   fi = Red_i[t * 8];
        #pragma unroll
        for (int k = 1; k < 8; ++k) {
            float v = Red_d[t * 8 + k];
            int  ii = Red_i[t * 8 + k];
            if (v < fv || (v == fv && ii < fi)) { fv = v; fi = ii; }
        }
        out_idx[tok0 + t] = (float)fi;
        atomicAdd(&counts[fi], 1u);
    }
}

// ---------------- gather quantized + loss ----------------
__global__ __launch_bounds__(256) void k_gather(const float* __restrict__ x,
                                                const float* __restrict__ w,
                                                const float* __restrict__ out_idx,
                                                float* __restrict__ outq,
                                                float* __restrict__ loss_acc) {
    int gid = blockIdx.x * 256 + threadIdx.x;
    int token = gid >> 6;
    int d4 = gid & 63;
    int idx = (int)out_idx[token];
    float4 q  = ((const float4*)(w + (size_t)idx * DIM))[d4];
    float4 xv = ((const float4*)x)[gid];
    ((float4*)outq)[gid] = q;
    float dx = q.x - xv.x, dy = q.y - xv.y, dz = q.z - xv.z, dw = q.w - xv.w;
    float sse = dx * dx + dy * dy + dz * dz + dw * dw;
    #pragma unroll
    for (int off = 32; off > 0; off >>= 1) sse += __shfl_down(sse, off, 64);
    __shared__ float sred[4];
    int lane = threadIdx.x & 63, wv = threadIdx.x >> 6;
    if (lane == 0) sred[wv] = sse;
    __syncthreads();
    if (threadIdx.x == 0)
        atomicAdd(loss_acc, sred[0] + sred[1] + sred[2] + sred[3]);
}

// ---------------- one-hot encodings ----------------
__global__ __launch_bounds__(256) void k_onehot(const float* __restrict__ out_idx,
                                                float* __restrict__ enc) {
    int token = blockIdx.x;
    int idx = (int)out_idx[token];
    float4* row = (float4*)(enc + (size_t)token * N_EMB);
    #pragma unroll
    for (int p = 0; p < 4; ++p) {
        int g = threadIdx.x + 256 * p;
        float4 v = make_float4(0.f, 0.f, 0.f, 0.f);
        int d0 = g * 4;
        if (idx >= d0 && idx < d0 + 4) ((float*)&v)[idx - d0] = 1.0f;
        row[g] = v;
    }
}

// ---------------- perplexity + loss finalize ----------------
__global__ __launch_bounds__(256) void k_final(const unsigned int* __restrict__ counts,
                                               const float* __restrict__ loss_acc,
                                               float* __restrict__ out_perp,
                                               float* __restrict__ out_loss) {
    __shared__ float sred[4];
    int t = threadIdx.x;
    float h = 0.f;
    for (int k = t; k < N_EMB; k += 256) {
        float p = (float)counts[k] * (1.0f / N_TOK);
        h += p * logf(p + 1e-10f);
    }
    #pragma unroll
    for (int off = 32; off > 0; off >>= 1) h += __shfl_down(h, off, 64);
    if ((t & 63) == 0) sred[t >> 6] = h;
    __syncthreads();
    if (t == 0) {
        float s = sred[0] + sred[1] + sred[2] + sred[3];
        *out_perp = expf(-s);
        *out_loss = loss_acc[0] * 1.25f / 8388608.0f;
    }
}

extern "C" void kernel_launch(void* const* d_in, const int* in_sizes, int n_in,
                              void* d_out, int out_size, void* d_ws, size_t ws_size,
                              hipStream_t stream) {
    const float* x = (const float*)d_in[0];
    const float* w = (const float*)d_in[1];
    float* out  = (float*)d_out;
    float* out0 = out;                       // quantized_st [32768*256]
    float* out1 = out0 + 8388608;            // perplexity   [1]
    float* out2 = out1 + 1;                  // encodings    [32768*4096]
    float* out3 = out2 + 134217728;          // indices      [32768] (as float)
    float* out4 = out3 + 32768;              // loss         [1]

    unsigned int* counts = (unsigned int*)d_ws;
    float* loss_acc = (float*)((char*)d_ws + 16384);
    float* e2_np    = (float*)((char*)d_ws + 16896);
    float* x2_np    = (float*)((char*)d_ws + 33280);

    // bf16 shuffled scratch inside the encodings region (18 MB of 536 MB),
    // 256B-aligned; k_onehot overwrites it after k_score_mfma consumed it.
    uintptr_t sb = ((uintptr_t)out2 + 255) & ~(uintptr_t)255;
    unsigned short* Xh = (unsigned short*)sb;     // 16 MB
    unsigned short* Wh = Xh + 8388608;            // 2 MB

    hipMemsetAsync(d_ws, 0, 16640, stream);
    k_norm_np<<<N_EMB / 256, 256, 0, stream>>>(w, e2_np, N_EMB);
    k_norm_np<<<N_TOK / 256, 256, 0, stream>>>(x, x2_np, N_TOK);
    k_shuf1<<<N_TOK * DIM / 8 / 256, 256, 0, stream>>>(x, Xh);
    k_shuf1<<<N_EMB * DIM / 8 / 256, 256, 0, stream>>>(w, Wh);
    k_score_mfma<<<N_TOK / 32, 256, 0, stream>>>(x, w, e2_np, x2_np,
                                                 Xh, Wh, out3, counts);
    k_gather<<<N_TOK * 64 / 256, 256, 0, stream>>>(x, w, out3, out0, loss_acc);
    k_onehot<<<N_TOK, 256, 0, stream>>>(out3, out2);
    k_final<<<1, 256, 0, stream>>>(counts, loss_acc, out1, out4);
}

// Round 10
// 845.883 us; speedup vs baseline: 1.1642x; 1.1429x over previous
//
#include <hip/hip_runtime.h>

#define N_TOK 32768
#define N_EMB 4096
#define DIM 256

typedef short bf16x8 __attribute__((ext_vector_type(8)));
typedef float f32x4 __attribute__((ext_vector_type(4)));
typedef unsigned short us8 __attribute__((ext_vector_type(8)));

// ---------------- ws layout (primary, ws_size >= 20 MB) ----------------
// [0, 16384)        counts    uint[4096]
// [16384, 16388)    loss_acc  float
// [16896, 33280)    e2_np     float[4096]
// [33280, 164352)   x2_np     float[32768]
// [1 MB, 17 MB)     Xh        bf16[32768*256] MFMA-shuffled
// [17 MB, 19 MB)    Wh        bf16[4096*256]  MFMA-shuffled
// Fallback (small ws): Xh/Wh in encodings region + separate k_onehot (r8 path).

static __device__ __forceinline__ unsigned short f2bf(float f) {
    unsigned int u = __float_as_uint(f);
    u = (u + 0x7fffu + ((u >> 16) & 1u)) >> 16;   // RTN-even
    return (unsigned short)u;
}

// ---------------- numpy-pairwise fp32 row norms (r3-proven bit-exact) ------
__device__ __forceinline__ float pw128_sq(const float4* a4) {
#pragma clang fp contract(off)
    float4 v0 = a4[0], v1 = a4[1];
    float r0 = v0.x * v0.x, r1 = v0.y * v0.y, r2 = v0.z * v0.z, r3 = v0.w * v0.w;
    float r4 = v1.x * v1.x, r5 = v1.y * v1.y, r6 = v1.z * v1.z, r7 = v1.w * v1.w;
    #pragma unroll
    for (int i = 1; i < 16; ++i) {
        v0 = a4[2 * i]; v1 = a4[2 * i + 1];
        float s;
        s = v0.x * v0.x; r0 += s;
        s = v0.y * v0.y; r1 += s;
        s = v0.z * v0.z; r2 += s;
        s = v0.w * v0.w; r3 += s;
        s = v1.x * v1.x; r4 += s;
        s = v1.y * v1.y; r5 += s;
        s = v1.z * v1.z; r6 += s;
        s = v1.w * v1.w; r7 += s;
    }
    return ((r0 + r1) + (r2 + r3)) + ((r4 + r5) + (r6 + r7));
}

__global__ __launch_bounds__(256) void k_norm_np(const float* __restrict__ src,
                                                 float* __restrict__ dst, int nrows) {
#pragma clang fp contract(off)
    int row = blockIdx.x * 256 + threadIdx.x;
    if (row >= nrows) return;
    const float4* a = (const float4*)(src + (size_t)row * DIM);
    float lo = pw128_sq(a);
    float hi = pw128_sq(a + 32);
    dst[row] = lo + hi;
}

// ---------------- bf16 cast + MFMA-fragment shuffle ----------------
__global__ __launch_bounds__(256) void k_shuf1(const float* __restrict__ src,
                                               unsigned short* __restrict__ hi) {
    int tid = blockIdx.x * 256 + threadIdx.x;
    int b = tid >> 6, lane = tid & 63;
    int T = b >> 3, C = b & 7;
    int row = T * 16 + (lane & 15);
    int col = C * 32 + (lane >> 4) * 8;
    const float* s = src + (size_t)row * DIM + col;
    us8 h;
    #pragma unroll
    for (int j = 0; j < 8; ++j) h[j] = f2bf(s[j]);
    *(us8*)(hi + (size_t)tid * 8) = h;
}

// ---- fused MFMA scoring: two-pass threshold + np-exact refine + epilogue ----
// r8-proven core. Added: (a) one-hot zero-fill drip-fed as nontemporal stores
// inside pass 1 (overlaps 512 KB/block of HBM writes with MFMA; nt protects
// L2-resident Wh); (b) epilogue writes 1.0f scatter + quantized gather + loss.
__global__ __launch_bounds__(256, 4) void k_score_mfma(
        const float* __restrict__ x, const float* __restrict__ w,
        const float* __restrict__ e2_np, const float* __restrict__ x2_np,
        const unsigned short* __restrict__ Xh,
        const unsigned short* __restrict__ Wh,
        float* __restrict__ out_idx, unsigned int* __restrict__ counts,
        float* enc,                       // nullable: fused one-hot
        float* __restrict__ outq, float* __restrict__ loss_acc) {
    __shared__ __align__(16) short Abuf[8192];   // [tile(2)][C(8)][lane][8] = 16 KB
    __shared__ float Tmax[4][32];
    __shared__ unsigned int ccnt[32];
    __shared__ int clist[32][16];
    __shared__ float Red_d[32 * 8];
    __shared__ int   Red_i[32 * 8];
    __shared__ float sred[4];

    const int t = threadIdx.x;
    const int wave = t >> 6, lane = t & 63;
    const int tok0 = blockIdx.x * 32;
    const int q = lane >> 4, c = lane & 15;

    // ---- stage A (2 tiles x 8 chunks x 1KB), r7-proven ----
    #pragma unroll
    for (int i = 0; i < 4; ++i) {
        int idx = wave * 4 + i;             // 0..15
        int tile = idx >> 3, C = idx & 7;
        int Tg = blockIdx.x * 2 + tile;
        const unsigned short* src = Xh + ((size_t)(Tg * 8 + C) * 64 + lane) * 8;
        __builtin_amdgcn_global_load_lds(
            (const __attribute__((address_space(1))) unsigned int*)src,
            (__attribute__((address_space(3))) unsigned int*)(Abuf + idx * 512),
            16, 0, 0);
    }
    if (t < 32) ccnt[t] = 0;
    __syncthreads();

    f32x4* ez = enc ? (f32x4*)(enc + (size_t)tok0 * N_EMB) : (f32x4*)0;
    const f32x4 zf4 = {0.f, 0.f, 0.f, 0.f};

    // ---- pass 1: per-token max dot; one-hot zero-fill drip-fed ----
    float vmax[8];
    #pragma unroll
    for (int s = 0; s < 8; ++s) vmax[s] = -3.4e38f;
    for (int jt = 0; jt < N_EMB; jt += 256) {
        const int U0 = (jt >> 4) + wave * 4;
        f32x4 acc[2][4] = {};
        #pragma unroll
        for (int C = 0; C < 8; ++C) {
            bf16x8 ah[2], bh[4];
            #pragma unroll
            for (int m = 0; m < 2; ++m)
                ah[m] = *(const bf16x8*)(Abuf + (size_t)(m * 8 + C) * 512 + lane * 8);
            #pragma unroll
            for (int n = 0; n < 4; ++n)
                bh[n] = *(const bf16x8*)(Wh + (((size_t)(U0 + n) * 8 + C) * 64 + lane) * 8);
            #pragma unroll
            for (int m = 0; m < 2; ++m)
                #pragma unroll
                for (int n = 0; n < 4; ++n)
                    acc[m][n] = __builtin_amdgcn_mfma_f32_16x16x32_bf16(ah[m], bh[n], acc[m][n], 0, 0, 0);
        }
        #pragma unroll
        for (int m = 0; m < 2; ++m)
            #pragma unroll
            for (int n = 0; n < 4; ++n)
                #pragma unroll
                for (int r = 0; r < 4; ++r)
                    vmax[m * 4 + r] = fmaxf(vmax[m * 4 + r], acc[m][n][r]);
        if (ez) {   // 8 x 16B nt zero-stores per thread per jt = 512 KB/block total
            int base = (jt >> 8) * 8 * 256 + t;
            #pragma unroll
            for (int j = 0; j < 8; ++j)
                __builtin_nontemporal_store(zf4, ez + base + j * 256);
        }
    }
    // reduce over the 16 c-lanes of each q-group
    #pragma unroll
    for (int off = 1; off < 16; off <<= 1)
        #pragma unroll
        for (int s = 0; s < 8; ++s)
            vmax[s] = fmaxf(vmax[s], __shfl_xor(vmax[s], off));
    if (c == 0) {
        #pragma unroll
        for (int m = 0; m < 2; ++m)
            #pragma unroll
            for (int r = 0; r < 4; ++r)
                Tmax[wave][m * 16 + q * 4 + r] = vmax[m * 4 + r];
    }
    __syncthreads();
    if (t < 32) {
        float mx = fmaxf(fmaxf(Tmax[0][t], Tmax[1][t]),
                         fmaxf(Tmax[2][t], Tmax[3][t]));
        Tmax[0][t] = mx - 1.5e-4f;     // threshold (r6/r7-proven margin)
    }
    __syncthreads();
    float thr[8];
    #pragma unroll
    for (int m = 0; m < 2; ++m)
        #pragma unroll
        for (int r = 0; r < 4; ++r)
            thr[m * 4 + r] = Tmax[0][m * 16 + q * 4 + r];

    // ---- pass 2: recompute (bit-identical), collect candidates ----
    for (int jt = 0; jt < N_EMB; jt += 256) {
        const int U0 = (jt >> 4) + wave * 4;
        f32x4 acc[2][4] = {};
        #pragma unroll
        for (int C = 0; C < 8; ++C) {
            bf16x8 ah[2], bh[4];
            #pragma unroll
            for (int m = 0; m < 2; ++m)
                ah[m] = *(const bf16x8*)(Abuf + (size_t)(m * 8 + C) * 512 + lane * 8);
            #pragma unroll
            for (int n = 0; n < 4; ++n)
                bh[n] = *(const bf16x8*)(Wh + (((size_t)(U0 + n) * 8 + C) * 64 + lane) * 8);
            #pragma unroll
            for (int m = 0; m < 2; ++m)
                #pragma unroll
                for (int n = 0; n < 4; ++n)
                    acc[m][n] = __builtin_amdgcn_mfma_f32_16x16x32_bf16(ah[m], bh[n], acc[m][n], 0, 0, 0);
        }
        #pragma unroll
        for (int m = 0; m < 2; ++m)
            #pragma unroll
            for (int n = 0; n < 4; ++n)
                #pragma unroll
                for (int r = 0; r < 4; ++r)
                    if (acc[m][n][r] >= thr[m * 4 + r]) {
                        int tokl = m * 16 + q * 4 + r;
                        int code = (U0 + n) * 16 + c;
                        unsigned int p = atomicAdd(&ccnt[tokl], 1u);
                        if (p < 16) clist[tokl][p] = code;
                    }
    }
    __syncthreads();

    // ---- np-fp32-exact refinement: 8 threads/token over the list ----
    {
        int token = t >> 3, slot = t & 7;
        int cnt = (int)ccnt[token]; if (cnt > 16) cnt = 16;
        float bd = 3.4e38f;
        int bi = 0x7fffffff;
        float x2 = x2_np[tok0 + token];
        const float4* xr = (const float4*)(x + (size_t)(tok0 + token) * DIM);
        for (int k = slot; k < cnt; k += 8) {
            int code = clist[token][k];
            const float4* wr = (const float4*)(w + (size_t)code * DIM);
            double dot = 0.0;
            for (int g = 0; g < 64; ++g) {
                float4 xv = xr[g];
                float4 wv = wr[g];
                dot += (double)xv.x * (double)wv.x;
                dot += (double)xv.y * (double)wv.y;
                dot += (double)xv.z * (double)wv.z;
                dot += (double)xv.w * (double)wv.w;
            }
            {
#pragma clang fp contract(off)
                float M  = (float)dot;          // BLAS sgemm entry (~2e-9)
                float S  = x2 + e2_np[code];    // np broadcast add (fp32)
                float dd = S - 2.0f * M;        // fp32 sub -> ulp bucket
                if (dd < bd || (dd == bd && code < bi)) { bd = dd; bi = code; }
            }
        }
        Red_d[token * 8 + slot] = bd;
        Red_i[token * 8 + slot] = bi;
    }
    __syncthreads();
    if (t < 32) {
        float fv = Red_d[t * 8];
        int   fi = Red_i[t * 8];
        #pragma unroll
        for (int k = 1; k < 8; ++k) {
            float v = Red_d[t * 8 + k];
            int  ii = Red_i[t * 8 + k];
            if (v < fv || (v == fv && ii < fi)) { fv = v; fi = ii; }
        }
        out_idx[tok0 + t] = (float)fi;
        atomicAdd(&counts[fi], 1u);
        ccnt[t] = (unsigned int)fi;   // publish for epilogue
    }
    __syncthreads();

    // ---- epilogue: 1.0f scatter + quantized gather + commitment loss ----
    {
        int token = t >> 3, slot = t & 7;
        int fi = (int)ccnt[token];
        // zero-stores for this row drained at the Tmax __syncthreads (vmcnt(0));
        // same-XCD L2 ordering makes this 1.0f land after them.
        if (enc && slot == 0)
            __builtin_nontemporal_store(1.0f, enc + (size_t)(tok0 + token) * N_EMB + fi);
        const f32x4* wr = (const f32x4*)(w + (size_t)fi * DIM);
        const f32x4* xr = (const f32x4*)(x + (size_t)(tok0 + token) * DIM);
        f32x4* oq = (f32x4*)(outq + (size_t)(tok0 + token) * DIM);
        float sse = 0.f;
        #pragma unroll
        for (int g0 = 0; g0 < 8; ++g0) {
            int g = slot * 8 + g0;
            f32x4 qv = wr[g];
            f32x4 xv = xr[g];
            __builtin_nontemporal_store(qv, oq + g);
            float dx = qv.x - xv.x, dy = qv.y - xv.y;
            float dz = qv.z - xv.z, dw = qv.w - xv.w;
            sse += dx * dx + dy * dy + dz * dz + dw * dw;
        }
        #pragma unroll
        for (int off = 32; off > 0; off >>= 1) sse += __shfl_down(sse, off, 64);
        if (lane == 0) sred[wave] = sse;
    }
    __syncthreads();
    if (t == 0)
        atomicAdd(loss_acc, sred[0] + sred[1] + sred[2] + sred[3]);
}

// ---------------- one-hot encodings (fallback path only) ----------------
__global__ __launch_bounds__(256) void k_onehot(const float* __restrict__ out_idx,
                                                float* __restrict__ enc) {
    int token = blockIdx.x;
    int idx = (int)out_idx[token];
    float4* row = (float4*)(enc + (size_t)token * N_EMB);
    #pragma unroll
    for (int p = 0; p < 4; ++p) {
        int g = threadIdx.x + 256 * p;
        float4 v = make_float4(0.f, 0.f, 0.f, 0.f);
        int d0 = g * 4;
        if (idx >= d0 && idx < d0 + 4) ((float*)&v)[idx - d0] = 1.0f;
        row[g] = v;
    }
}

// ---------------- perplexity + loss finalize ----------------
__global__ __launch_bounds__(256) void k_final(const unsigned int* __restrict__ counts,
                                               const float* __restrict__ loss_acc,
                                               float* __restrict__ out_perp,
                                               float* __restrict__ out_loss) {
    __shared__ float sred[4];
    int t = threadIdx.x;
    float h = 0.f;
    for (int k = t; k < N_EMB; k += 256) {
        float p = (float)counts[k] * (1.0f / N_TOK);
        h += p * logf(p + 1e-10f);
    }
    #pragma unroll
    for (int off = 32; off > 0; off >>= 1) h += __shfl_down(h, off, 64);
    if ((t & 63) == 0) sred[t >> 6] = h;
    __syncthreads();
    if (t == 0) {
        float s = sred[0] + sred[1] + sred[2] + sred[3];
        *out_perp = expf(-s);
        *out_loss = loss_acc[0] * 1.25f / 8388608.0f;
    }
}

extern "C" void kernel_launch(void* const* d_in, const int* in_sizes, int n_in,
                              void* d_out, int out_size, void* d_ws, size_t ws_size,
                              hipStream_t stream) {
    const float* x = (const float*)d_in[0];
    const float* w = (const float*)d_in[1];
    float* out  = (float*)d_out;
    float* out0 = out;                       // quantized_st [32768*256]
    float* out1 = out0 + 8388608;            // perplexity   [1]
    float* out2 = out1 + 1;                  // encodings    [32768*4096]
    float* out3 = out2 + 134217728;          // indices      [32768] (as float)
    float* out4 = out3 + 32768;              // loss         [1]

    unsigned int* counts = (unsigned int*)d_ws;
    float* loss_acc = (float*)((char*)d_ws + 16384);
    float* e2_np    = (float*)((char*)d_ws + 16896);
    float* x2_np    = (float*)((char*)d_ws + 33280);

    // Primary: scratch in d_ws (measured ws ~1.7 GB), one-hot fused into
    // k_score. Fallback (small ws): r8 layout + separate k_onehot.
    bool big_ws = ws_size >= (size_t)(20u * 1024u * 1024u);
    unsigned short *Xh, *Wh;
    float* enc_arg;
    if (big_ws) {
        Xh = (unsigned short*)((char*)d_ws + (1u << 20));   // 16 MB
        Wh = Xh + 8388608;                                   // 2 MB
        enc_arg = out2;
    } else {
        uintptr_t sb = ((uintptr_t)out2 + 255) & ~(uintptr_t)255;
        Xh = (unsigned short*)sb;
        Wh = Xh + 8388608;
        enc_arg = nullptr;
    }

    hipMemsetAsync(d_ws, 0, 16640, stream);
    k_norm_np<<<N_EMB / 256, 256, 0, stream>>>(w, e2_np, N_EMB);
    k_norm_np<<<N_TOK / 256, 256, 0, stream>>>(x, x2_np, N_TOK);
    k_shuf1<<<N_TOK * DIM / 8 / 256, 256, 0, stream>>>(x, Xh);
    k_shuf1<<<N_EMB * DIM / 8 / 256, 256, 0, stream>>>(w, Wh);
    k_score_mfma<<<N_TOK / 32, 256, 0, stream>>>(x, w, e2_np, x2_np, Xh, Wh,
                                                 out3, counts, enc_arg,
                                                 out0, loss_acc);
    if (!big_ws)
        k_onehot<<<N_TOK, 256, 0, stream>>>(out3, out2);
    k_final<<<1, 256, 0, stream>>>(counts, loss_acc, out1, out4);
}